// Round 1
// baseline (5315.847 us; speedup 1.0000x reference)
//
#include <hip/hip_runtime.h>
#include <hip/hip_bf16.h>

// Problem constants (from reference)
constexpr int Bc  = 2;
constexpr int Tc  = 2048;
constexpr int Dc  = 2048;
constexpr int Hc  = 32;
constexpr int KVc = 8;
constexpr int HDc = 64;
constexpr int Mrows = Bc * Tc;          // 4096
constexpr float SCALE = 0.125f;         // 1/sqrt(64)

// ---------------------------------------------------------------------------
// Tiled fp32 GEMM: C[M,N] = A[M,K] @ W[K,N], all row-major.
// BM=BN=64, BK=16, 256 threads (16x16), 4x4 micro-tile per thread.
// ---------------------------------------------------------------------------
__global__ __launch_bounds__(256) void gemm64(const float* __restrict__ A,
                                              const float* __restrict__ W,
                                              float* __restrict__ C,
                                              int M, int N, int K) {
    __shared__ float As[16][64];      // [k][m]
    __shared__ float Ws[16][68];      // [k][n], +4 pad keeps 16B alignment
    const int bm = blockIdx.y * 64;
    const int bn = blockIdx.x * 64;
    const int tx = threadIdx.x;       // 0..15 -> N
    const int ty = threadIdx.y;       // 0..15 -> M
    const int tid = ty * 16 + tx;

    // global loader indices
    const int arow = tid >> 2;            // 0..63
    const int acol = (tid & 3) * 4;       // 0,4,8,12
    const int wrow = tid >> 4;            // 0..15
    const int wcol = (tid & 15) * 4;      // 0..60

    float acc[4][4] = {};

    for (int k0 = 0; k0 < K; k0 += 16) {
        float4 av = *(const float4*)(A + (size_t)(bm + arow) * K + k0 + acol);
        float4 wv = *(const float4*)(W + (size_t)(k0 + wrow) * N + bn + wcol);
        __syncthreads();   // previous iter's LDS reads done before overwrite
        As[acol + 0][arow] = av.x;
        As[acol + 1][arow] = av.y;
        As[acol + 2][arow] = av.z;
        As[acol + 3][arow] = av.w;
        *(float4*)&Ws[wrow][wcol] = wv;
        __syncthreads();
#pragma unroll
        for (int kk = 0; kk < 16; ++kk) {
            float4 a4 = *(const float4*)&As[kk][ty * 4];
            float4 w4 = *(const float4*)&Ws[kk][tx * 4];
            acc[0][0] += a4.x * w4.x; acc[0][1] += a4.x * w4.y;
            acc[0][2] += a4.x * w4.z; acc[0][3] += a4.x * w4.w;
            acc[1][0] += a4.y * w4.x; acc[1][1] += a4.y * w4.y;
            acc[1][2] += a4.y * w4.z; acc[1][3] += a4.y * w4.w;
            acc[2][0] += a4.z * w4.x; acc[2][1] += a4.z * w4.y;
            acc[2][2] += a4.z * w4.z; acc[2][3] += a4.z * w4.w;
            acc[3][0] += a4.w * w4.x; acc[3][1] += a4.w * w4.y;
            acc[3][2] += a4.w * w4.z; acc[3][3] += a4.w * w4.w;
        }
    }
#pragma unroll
    for (int i = 0; i < 4; ++i) {
        float4 o = make_float4(acc[i][0], acc[i][1], acc[i][2], acc[i][3]);
        *(float4*)(C + (size_t)(bm + ty * 4 + i) * N + bn + tx * 4) = o;
    }
}

// ---------------------------------------------------------------------------
// In-place RoPE over [B*T, nHeads, HD] buffer. One thread per (row, head,
// d<32) pair. cos/sin are [T, 64] with c[t,d] == c[t,d+32].
// ---------------------------------------------------------------------------
__global__ void rope_kernel(float* __restrict__ qk,
                            const float* __restrict__ cosT,
                            const float* __restrict__ sinT,
                            int nHeads, int total) {
    int idx = blockIdx.x * blockDim.x + threadIdx.x;
    if (idx >= total) return;
    int d   = idx & 31;
    int h   = (idx >> 5) % nHeads;
    int row = idx / (32 * nHeads);        // b*T + t
    int t   = row & (Tc - 1);
    float c = cosT[t * HDc + d];
    float s = sinT[t * HDc + d];
    float* p = qk + ((size_t)row * nHeads + h) * HDc;
    float x0 = p[d];
    float x1 = p[d + 32];
    p[d]      = x0 * c - x1 * s;
    p[d + 32] = x1 * c + x0 * s;
}

// ---------------------------------------------------------------------------
// Causal GQA attention, thread-per-query-row online softmax.
// q: [B*T, H, HD] (RoPE'd, in ws), k/v: [B*T, KV, HD] (RoPE'd k).
// Consecutive lanes = consecutive t of the same (b,h) -> the whole wave
// reads the SAME k/v row each step (broadcast-coalesced).
// y out: [B*T, H, HD] == [M, 2048] row-major.
// ---------------------------------------------------------------------------
__global__ __launch_bounds__(256) void attn_kernel(const float* __restrict__ q,
                                                   const float* __restrict__ k,
                                                   const float* __restrict__ v,
                                                   float* __restrict__ y) {
    int gid = blockIdx.x * blockDim.x + threadIdx.x;   // B*H*T total
    int t = gid & (Tc - 1);
    int h = (gid >> 11) & (Hc - 1);
    int b = gid >> 16;                                  // T*H = 65536
    int g = h >> 2;                                     // kv head (N_REP=4)

    const float* qp = q + ((size_t)(b * Tc + t) * Hc + h) * HDc;
    float qr[64];
#pragma unroll
    for (int i = 0; i < 16; ++i) {
        float4 qq = *(const float4*)(qp + 4 * i);
        qr[4 * i + 0] = qq.x * SCALE;
        qr[4 * i + 1] = qq.y * SCALE;
        qr[4 * i + 2] = qq.z * SCALE;
        qr[4 * i + 3] = qq.w * SCALE;
    }

    float m = -1e30f, l = 0.0f;
    float acc[64];
#pragma unroll
    for (int i = 0; i < 64; ++i) acc[i] = 0.0f;

    const float* kbase = k + ((size_t)b * Tc * KVc + g) * HDc;
    const float* vbase = v + ((size_t)b * Tc * KVc + g) * HDc;
    const int smax = t | 63;    // wave-uniform loop bound (lanes share upper 6 bits of t)

    for (int s = 0; s <= smax; ++s) {
        const float* kp = kbase + (size_t)s * (KVc * HDc);
        float sc = 0.0f;
#pragma unroll
        for (int i = 0; i < 16; ++i) {
            float4 kk = *(const float4*)(kp + 4 * i);
            sc += qr[4 * i + 0] * kk.x + qr[4 * i + 1] * kk.y
                + qr[4 * i + 2] * kk.z + qr[4 * i + 3] * kk.w;
        }
        sc = (s <= t) ? sc : -1e30f;
        float mnew = fmaxf(m, sc);
        float corr = __expf(m - mnew);       // first iter: exp(-inf - finite) = 0
        float p    = __expf(sc - mnew);
        l = l * corr + p;
        const float* vp = vbase + (size_t)s * (KVc * HDc);
#pragma unroll
        for (int i = 0; i < 16; ++i) {
            float4 vv = *(const float4*)(vp + 4 * i);
            acc[4 * i + 0] = acc[4 * i + 0] * corr + p * vv.x;
            acc[4 * i + 1] = acc[4 * i + 1] * corr + p * vv.y;
            acc[4 * i + 2] = acc[4 * i + 2] * corr + p * vv.z;
            acc[4 * i + 3] = acc[4 * i + 3] * corr + p * vv.w;
        }
        m = mnew;
    }

    float inv = 1.0f / l;
    float* yp = y + ((size_t)(b * Tc + t) * Hc + h) * HDc;
#pragma unroll
    for (int i = 0; i < 16; ++i) {
        float4 o = make_float4(acc[4 * i + 0] * inv, acc[4 * i + 1] * inv,
                               acc[4 * i + 2] * inv, acc[4 * i + 3] * inv);
        *(float4*)(yp + 4 * i) = o;
    }
}

// ---------------------------------------------------------------------------
extern "C" void kernel_launch(void* const* d_in, const int* in_sizes, int n_in,
                              void* d_out, int out_size, void* d_ws, size_t ws_size,
                              hipStream_t stream) {
    const float* x    = (const float*)d_in[0];
    const float* Wq   = (const float*)d_in[1];
    const float* Wk   = (const float*)d_in[2];
    const float* Wv   = (const float*)d_in[3];
    const float* Wo   = (const float*)d_in[4];
    const float* cosT = (const float*)d_in[5];
    const float* sinT = (const float*)d_in[6];
    float* out = (float*)d_out;

    // workspace layout (fp32): qbuf[4096*2048] kbuf[4096*512] vbuf[4096*512] ybuf[4096*2048]
    float* qbuf = (float*)d_ws;
    float* kbuf = qbuf + (size_t)Mrows * (Hc * HDc);
    float* vbuf = kbuf + (size_t)Mrows * (KVc * HDc);
    float* ybuf = vbuf + (size_t)Mrows * (KVc * HDc);

    dim3 blk(16, 16);
    // Q = x @ Wq  [4096, 2048]
    gemm64<<<dim3((Hc * HDc) / 64, Mrows / 64), blk, 0, stream>>>(x, Wq, qbuf, Mrows, Hc * HDc, Dc);
    // K = x @ Wk  [4096, 512]
    gemm64<<<dim3((KVc * HDc) / 64, Mrows / 64), blk, 0, stream>>>(x, Wk, kbuf, Mrows, KVc * HDc, Dc);
    // V = x @ Wv  [4096, 512]
    gemm64<<<dim3((KVc * HDc) / 64, Mrows / 64), blk, 0, stream>>>(x, Wv, vbuf, Mrows, KVc * HDc, Dc);

    // RoPE in-place on q and k
    {
        int totalQ = Mrows * Hc * 32;
        rope_kernel<<<(totalQ + 255) / 256, 256, 0, stream>>>(qbuf, cosT, sinT, Hc, totalQ);
        int totalK = Mrows * KVc * 32;
        rope_kernel<<<(totalK + 255) / 256, 256, 0, stream>>>(kbuf, cosT, sinT, KVc, totalK);
    }

    // attention: one thread per (b,h,t) row
    {
        int total = Bc * Hc * Tc;     // 131072
        attn_kernel<<<total / 256, 256, 0, stream>>>(qbuf, kbuf, vbuf, ybuf);
    }

    // out = y @ Wo  [4096, 2048]
    gemm64<<<dim3(Dc / 64, Mrows / 64), blk, 0, stream>>>(ybuf, Wo, out, Mrows, Dc, Dc);
}

// Round 2
// 3064.610 us; speedup vs baseline: 1.7346x; 1.7346x over previous
//
#include <hip/hip_runtime.h>
#include <hip/hip_bf16.h>

// Problem constants (from reference)
constexpr int Bc  = 2;
constexpr int Tc  = 2048;
constexpr int Dc  = 2048;
constexpr int Hc  = 32;
constexpr int KVc = 8;
constexpr int HDc = 64;
constexpr int Mrows = Bc * Tc;          // 4096
constexpr float SCALE = 0.125f;         // 1/sqrt(64)

// ---------------------------------------------------------------------------
// Tiled fp32 GEMM: C[M,N] = A[M,K] @ W[K,N], all row-major.
// BM=BN=64, BK=16, 256 threads (16x16), 4x4 micro-tile per thread.
// ---------------------------------------------------------------------------
__global__ __launch_bounds__(256) void gemm64(const float* __restrict__ A,
                                              const float* __restrict__ W,
                                              float* __restrict__ C,
                                              int M, int N, int K) {
    __shared__ float As[16][64];      // [k][m]
    __shared__ float Ws[16][68];      // [k][n], +4 pad keeps 16B alignment
    const int bm = blockIdx.y * 64;
    const int bn = blockIdx.x * 64;
    const int tx = threadIdx.x;       // 0..15 -> N
    const int ty = threadIdx.y;       // 0..15 -> M
    const int tid = ty * 16 + tx;

    const int arow = tid >> 2;            // 0..63
    const int acol = (tid & 3) * 4;       // 0,4,8,12
    const int wrow = tid >> 4;            // 0..15
    const int wcol = (tid & 15) * 4;      // 0..60

    float acc[4][4] = {};

    for (int k0 = 0; k0 < K; k0 += 16) {
        float4 av = *(const float4*)(A + (size_t)(bm + arow) * K + k0 + acol);
        float4 wv = *(const float4*)(W + (size_t)(k0 + wrow) * N + bn + wcol);
        __syncthreads();
        As[acol + 0][arow] = av.x;
        As[acol + 1][arow] = av.y;
        As[acol + 2][arow] = av.z;
        As[acol + 3][arow] = av.w;
        *(float4*)&Ws[wrow][wcol] = wv;
        __syncthreads();
#pragma unroll
        for (int kk = 0; kk < 16; ++kk) {
            float4 a4 = *(const float4*)&As[kk][ty * 4];
            float4 w4 = *(const float4*)&Ws[kk][tx * 4];
            acc[0][0] += a4.x * w4.x; acc[0][1] += a4.x * w4.y;
            acc[0][2] += a4.x * w4.z; acc[0][3] += a4.x * w4.w;
            acc[1][0] += a4.y * w4.x; acc[1][1] += a4.y * w4.y;
            acc[1][2] += a4.y * w4.z; acc[1][3] += a4.y * w4.w;
            acc[2][0] += a4.z * w4.x; acc[2][1] += a4.z * w4.y;
            acc[2][2] += a4.z * w4.z; acc[2][3] += a4.z * w4.w;
            acc[3][0] += a4.w * w4.x; acc[3][1] += a4.w * w4.y;
            acc[3][2] += a4.w * w4.z; acc[3][3] += a4.w * w4.w;
        }
    }
#pragma unroll
    for (int i = 0; i < 4; ++i) {
        float4 o = make_float4(acc[i][0], acc[i][1], acc[i][2], acc[i][3]);
        *(float4*)(C + (size_t)(bm + ty * 4 + i) * N + bn + tx * 4) = o;
    }
}

// ---------------------------------------------------------------------------
// In-place RoPE over [B*T, nHeads, HD] buffer.
// ---------------------------------------------------------------------------
__global__ void rope_kernel(float* __restrict__ qk,
                            const float* __restrict__ cosT,
                            const float* __restrict__ sinT,
                            int nHeads, int total) {
    int idx = blockIdx.x * blockDim.x + threadIdx.x;
    if (idx >= total) return;
    int d   = idx & 31;
    int h   = (idx >> 5) % nHeads;
    int row = idx / (32 * nHeads);        // b*T + t
    int t   = row & (Tc - 1);
    float c = cosT[t * HDc + d];
    float s = sinT[t * HDc + d];
    float* p = qk + ((size_t)row * nHeads + h) * HDc;
    float x0 = p[d];
    float x1 = p[d + 32];
    p[d]      = x0 * c - x1 * s;
    p[d + 32] = x1 * c + x0 * s;
}

// ---------------------------------------------------------------------------
// Block-tiled fp32 flash attention.
// Block = 128 threads = 128 consecutive queries of one (b,h).
// K/V tiles (TK=32 keys x 64 dim) double-buffered in LDS via
// global_load_lds; all LDS reads are wave-broadcast (conflict-free).
// Online softmax per 8-key chunk (statically indexed arrays only).
// ---------------------------------------------------------------------------
constexpr int TQ = 128;
constexpr int TK = 32;

__device__ __forceinline__ void load_lds16(const float* g, float* l) {
    __builtin_amdgcn_global_load_lds(
        (const __attribute__((address_space(1))) unsigned int*)g,
        (__attribute__((address_space(3))) unsigned int*)l,
        16, 0, 0);
}

__global__ __launch_bounds__(128) void attn_tiled(const float* __restrict__ q,
                                                  const float* __restrict__ k,
                                                  const float* __restrict__ v,
                                                  float* __restrict__ y) {
    __shared__ float Ks[2][TK][HDc];   // 8 KB per buffer
    __shared__ float Vs[2][TK][HDc];

    const int tid  = threadIdx.x;
    const int lane = tid & 63;
    const int w    = tid >> 6;         // wave id, uniform per wave
    const int qt0  = blockIdx.x * TQ;
    const int h    = blockIdx.y;
    const int b    = blockIdx.z;
    const int g    = h >> 2;           // kv head (N_REP = 4)
    const int myq  = qt0 + tid;

    const float* kbase = k + ((size_t)b * Tc * KVc + g) * HDc;
    const float* vbase = v + ((size_t)b * Tc * KVc + g) * HDc;

    // q row into registers, pre-scaled
    const float* qp = q + ((size_t)(b * Tc + myq) * Hc + h) * HDc;
    float qr[HDc];
#pragma unroll
    for (int i = 0; i < 16; ++i) {
        float4 qq = *(const float4*)(qp + 4 * i);
        qr[4 * i + 0] = qq.x * SCALE;
        qr[4 * i + 1] = qq.y * SCALE;
        qr[4 * i + 2] = qq.z * SCALE;
        qr[4 * i + 3] = qq.w * SCALE;
    }

    float m = -1e30f, l = 0.0f;
    float acc[HDc];
#pragma unroll
    for (int i = 0; i < HDc; ++i) acc[i] = 0.0f;

    const int nkv = (qt0 + TQ) / TK;   // kv tiles, uniform per block

    // --- staging helper: wave w loads chunks {w, w+2, w+4, w+6} ---
    auto stage = [&](int buf, int tile) {
        const int krow0 = tile * TK;
        const int srow  = (lane >> 4);         // 0..3 within chunk
        const int d     = (lane & 15) * 4;
#pragma unroll
        for (int p = 0; p < 4; ++p) {
            const int chunk = p * 2 + w;       // 0..7, uniform per wave
            const int s = chunk * 4 + srow;    // key row within tile
            const float* gk = kbase + (size_t)(krow0 + s) * (KVc * HDc) + d;
            const float* gv = vbase + (size_t)(krow0 + s) * (KVc * HDc) + d;
            load_lds16(gk, &Ks[buf][chunk * 4][0]);   // wave-uniform LDS base
            load_lds16(gv, &Vs[buf][chunk * 4][0]);
        }
    };

    stage(0, 0);

    for (int t = 0; t < nkv; ++t) {
        __syncthreads();                 // tile t staged (vmcnt drained @ barrier)
        if (t + 1 < nkv) stage((t + 1) & 1, t + 1);   // prefetch next tile
        const int bsel = t & 1;
        const int kv0  = t * TK;
        const float* Kb = &Ks[bsel][0][0];
        const float* Vb = &Vs[bsel][0][0];

        for (int c = 0; c < 4; ++c) {            // 4 chunks of 8 keys
            const int kvc = kv0 + c * 8;
            float p[8];
            float cmax = -1e30f;
#pragma unroll
            for (int j = 0; j < 8; ++j) {
                const float* kr = Kb + (c * 8 + j) * HDc;
                float sc = 0.0f;
#pragma unroll
                for (int i = 0; i < 16; ++i) {
                    float4 kk = *(const float4*)(kr + 4 * i);
                    sc += qr[4 * i + 0] * kk.x + qr[4 * i + 1] * kk.y
                        + qr[4 * i + 2] * kk.z + qr[4 * i + 3] * kk.w;
                }
                sc = (kvc + j <= myq) ? sc : -1e30f;
                p[j] = sc;
                cmax = fmaxf(cmax, sc);
            }
            if (cmax > m) {                       // rescale only when max grows
                float corr = __expf(m - cmax);
                l *= corr;
#pragma unroll
                for (int i = 0; i < HDc; ++i) acc[i] *= corr;
                m = cmax;
            }
            float psum = 0.0f;
#pragma unroll
            for (int j = 0; j < 8; ++j) {
                p[j] = __expf(p[j] - m);          // masked keys -> exp(-huge) = 0
                psum += p[j];
            }
            l += psum;
#pragma unroll
            for (int j = 0; j < 8; ++j) {
                const float* vr = Vb + (c * 8 + j) * HDc;
#pragma unroll
                for (int i = 0; i < 16; ++i) {
                    float4 vv = *(const float4*)(vr + 4 * i);
                    acc[4 * i + 0] += p[j] * vv.x;
                    acc[4 * i + 1] += p[j] * vv.y;
                    acc[4 * i + 2] += p[j] * vv.z;
                    acc[4 * i + 3] += p[j] * vv.w;
                }
            }
        }
    }

    float inv = 1.0f / l;
    float* yp = y + ((size_t)(b * Tc + myq) * Hc + h) * HDc;
#pragma unroll
    for (int i = 0; i < 16; ++i) {
        float4 o = make_float4(acc[4 * i + 0] * inv, acc[4 * i + 1] * inv,
                               acc[4 * i + 2] * inv, acc[4 * i + 3] * inv);
        *(float4*)(yp + 4 * i) = o;
    }
}

// ---------------------------------------------------------------------------
extern "C" void kernel_launch(void* const* d_in, const int* in_sizes, int n_in,
                              void* d_out, int out_size, void* d_ws, size_t ws_size,
                              hipStream_t stream) {
    const float* x    = (const float*)d_in[0];
    const float* Wq   = (const float*)d_in[1];
    const float* Wk   = (const float*)d_in[2];
    const float* Wv   = (const float*)d_in[3];
    const float* Wo   = (const float*)d_in[4];
    const float* cosT = (const float*)d_in[5];
    const float* sinT = (const float*)d_in[6];
    float* out = (float*)d_out;

    float* qbuf = (float*)d_ws;
    float* kbuf = qbuf + (size_t)Mrows * (Hc * HDc);
    float* vbuf = kbuf + (size_t)Mrows * (KVc * HDc);
    float* ybuf = vbuf + (size_t)Mrows * (KVc * HDc);

    dim3 blk(16, 16);
    gemm64<<<dim3((Hc * HDc) / 64, Mrows / 64), blk, 0, stream>>>(x, Wq, qbuf, Mrows, Hc * HDc, Dc);
    gemm64<<<dim3((KVc * HDc) / 64, Mrows / 64), blk, 0, stream>>>(x, Wk, kbuf, Mrows, KVc * HDc, Dc);
    gemm64<<<dim3((KVc * HDc) / 64, Mrows / 64), blk, 0, stream>>>(x, Wv, vbuf, Mrows, KVc * HDc, Dc);

    {
        int totalQ = Mrows * Hc * 32;
        rope_kernel<<<(totalQ + 255) / 256, 256, 0, stream>>>(qbuf, cosT, sinT, Hc, totalQ);
        int totalK = Mrows * KVc * 32;
        rope_kernel<<<(totalK + 255) / 256, 256, 0, stream>>>(kbuf, cosT, sinT, KVc, totalK);
    }

    // flash attention: 1024 blocks of 128 threads
    attn_tiled<<<dim3(Tc / TQ, Hc, Bc), 128, 0, stream>>>(qbuf, kbuf, vbuf, ybuf);

    gemm64<<<dim3(Dc / 64, Mrows / 64), blk, 0, stream>>>(ybuf, Wo, out, Mrows, Dc, Dc);
}

// Round 3
// 1667.490 us; speedup vs baseline: 3.1879x; 1.8379x over previous
//
#include <hip/hip_runtime.h>
#include <hip/hip_bf16.h>

// Problem constants (from reference)
constexpr int Bc  = 2;
constexpr int Tc  = 2048;
constexpr int Dc  = 2048;
constexpr int Hc  = 32;
constexpr int KVc = 8;
constexpr int HDc = 64;
constexpr int Mrows = Bc * Tc;          // 4096
constexpr float SCALE = 0.125f;         // 1/sqrt(64)

typedef __attribute__((ext_vector_type(8))) short  bf16x8;
typedef __attribute__((ext_vector_type(4))) short  short4v;
typedef __attribute__((ext_vector_type(4))) float  f32x4;

__device__ __forceinline__ short f2bf(float f) {     // fp32 -> bf16 (RNE)
    unsigned u = __builtin_bit_cast(unsigned, f);
    unsigned r = (u + 0x7FFFu + ((u >> 16) & 1u)) >> 16;
    return (short)(unsigned short)r;
}

// ---------------------------------------------------------------------------
// Tiled fp32 GEMM: C[M,N] = A[M,K] @ W[K,N]  (unchanged from round 1)
// ---------------------------------------------------------------------------
__global__ __launch_bounds__(256) void gemm64(const float* __restrict__ A,
                                              const float* __restrict__ W,
                                              float* __restrict__ C,
                                              int M, int N, int K) {
    __shared__ float As[16][64];
    __shared__ float Ws[16][68];
    const int bm = blockIdx.y * 64;
    const int bn = blockIdx.x * 64;
    const int tx = threadIdx.x;
    const int ty = threadIdx.y;
    const int tid = ty * 16 + tx;

    const int arow = tid >> 2;
    const int acol = (tid & 3) * 4;
    const int wrow = tid >> 4;
    const int wcol = (tid & 15) * 4;

    float acc[4][4] = {};

    for (int k0 = 0; k0 < K; k0 += 16) {
        float4 av = *(const float4*)(A + (size_t)(bm + arow) * K + k0 + acol);
        float4 wv = *(const float4*)(W + (size_t)(k0 + wrow) * N + bn + wcol);
        __syncthreads();
        As[acol + 0][arow] = av.x;
        As[acol + 1][arow] = av.y;
        As[acol + 2][arow] = av.z;
        As[acol + 3][arow] = av.w;
        *(float4*)&Ws[wrow][wcol] = wv;
        __syncthreads();
#pragma unroll
        for (int kk = 0; kk < 16; ++kk) {
            float4 a4 = *(const float4*)&As[kk][ty * 4];
            float4 w4 = *(const float4*)&Ws[kk][tx * 4];
            acc[0][0] += a4.x * w4.x; acc[0][1] += a4.x * w4.y;
            acc[0][2] += a4.x * w4.z; acc[0][3] += a4.x * w4.w;
            acc[1][0] += a4.y * w4.x; acc[1][1] += a4.y * w4.y;
            acc[1][2] += a4.y * w4.z; acc[1][3] += a4.y * w4.w;
            acc[2][0] += a4.z * w4.x; acc[2][1] += a4.z * w4.y;
            acc[2][2] += a4.z * w4.z; acc[2][3] += a4.z * w4.w;
            acc[3][0] += a4.w * w4.x; acc[3][1] += a4.w * w4.y;
            acc[3][2] += a4.w * w4.z; acc[3][3] += a4.w * w4.w;
        }
    }
#pragma unroll
    for (int i = 0; i < 4; ++i) {
        float4 o = make_float4(acc[i][0], acc[i][1], acc[i][2], acc[i][3]);
        *(float4*)(C + (size_t)(bm + ty * 4 + i) * N + bn + tx * 4) = o;
    }
}

// ---------------------------------------------------------------------------
// In-place RoPE over [B*T, nHeads, HD] buffer.
// ---------------------------------------------------------------------------
__global__ void rope_kernel(float* __restrict__ qk,
                            const float* __restrict__ cosT,
                            const float* __restrict__ sinT,
                            int nHeads, int total) {
    int idx = blockIdx.x * blockDim.x + threadIdx.x;
    if (idx >= total) return;
    int d   = idx & 31;
    int h   = (idx >> 5) % nHeads;
    int row = idx / (32 * nHeads);
    int t   = row & (Tc - 1);
    float c = cosT[t * HDc + d];
    float s = sinT[t * HDc + d];
    float* p = qk + ((size_t)row * nHeads + h) * HDc;
    float x0 = p[d];
    float x1 = p[d + 32];
    p[d]      = x0 * c - x1 * s;
    p[d + 32] = x1 * c + x0 * s;
}

// ---------------------------------------------------------------------------
// bf16 MFMA flash attention.
// Block = 256 thr = 4 waves; wave w owns 16 queries (qt0+16w..+15) x 64 dims.
// KV tiles of 64 keys: K staged row-major bf16 with 16B-unit XOR swizzle
// (^ row&7) -> conflict-free ds_read_b128 B-frags; V staged transposed
// (Vt[d][key], stride 72 = 16B-aligned rows).
// S via mfma_f32_16x16x32_bf16 (C: col=key=lane&15, row=q=(lane>>4)*4+reg);
// online softmax with 16-lane shfl_xor reduces; P -> per-wave LDS tile to
// re-layout as the PV A-fragment.
// ---------------------------------------------------------------------------
__global__ __launch_bounds__(256) void attn_mfma(const float* __restrict__ q,
                                                 const float* __restrict__ k,
                                                 const float* __restrict__ v,
                                                 float* __restrict__ y) {
    __shared__ short Ks[64 * 64];        // 8 KB, swizzled row-major K tile
    __shared__ short Vt[64][72];         // 9 KB, transposed V tile
    __shared__ short Ps[4][16][72];      // 9 KB, per-wave P tiles

    const int tid = threadIdx.x;
    const int l   = tid & 63;
    const int w   = tid >> 6;
    const int lr  = l & 15;              // MFMA col lane
    const int lg  = l >> 4;              // MFMA k-group
    const int qt0 = blockIdx.x * 64;
    const int h   = blockIdx.y;
    const int b   = blockIdx.z;
    const int g   = h >> 2;              // kv head (N_REP=4)
    const int qw0 = qt0 + w * 16;

    // ---- Q A-fragments (dims s*32 + lg*8 .. +7 of row qw0+lr), pre-scaled
    bf16x8 qf[2];
    {
        const float* qrow = q + ((size_t)(b * Tc + qw0 + lr) * Hc + h) * HDc;
#pragma unroll
        for (int s = 0; s < 2; ++s) {
            f32x4 a0 = *(const f32x4*)(qrow + s * 32 + lg * 8);
            f32x4 a1 = *(const f32x4*)(qrow + s * 32 + lg * 8 + 4);
            bf16x8 t;
            t[0] = f2bf(a0[0] * SCALE); t[1] = f2bf(a0[1] * SCALE);
            t[2] = f2bf(a0[2] * SCALE); t[3] = f2bf(a0[3] * SCALE);
            t[4] = f2bf(a1[0] * SCALE); t[5] = f2bf(a1[1] * SCALE);
            t[6] = f2bf(a1[2] * SCALE); t[7] = f2bf(a1[3] * SCALE);
            qf[s] = t;
        }
    }

    f32x4 o[4];
#pragma unroll
    for (int i = 0; i < 4; ++i) o[i] = f32x4{0.f, 0.f, 0.f, 0.f};
    float mr[4], ls[4];
#pragma unroll
    for (int i = 0; i < 4; ++i) { mr[i] = -1e30f; ls[i] = 0.f; }

    const float* kb_ = k + ((size_t)b * Tc * KVc + g) * HDc;
    const float* vb_ = v + ((size_t)b * Tc * KVc + g) * HDc;
    const int ntiles = qt0 / 64 + 1;

    // staging index precompute
    const int kd0   = (tid & 15) * 4;        // K: dim start (float4)
    const int kunit = kd0 >> 3;              // 16B unit within row
    const int khalf = (kd0 & 4) << 1;        // 0 or 8 byte half
    const int vkey  = (tid & 31) * 2;        // V: key pair
    const int vd0   = (tid >> 5) * 8;        // V: dim start

    for (int t = 0; t < ntiles; ++t) {
        const int kv0 = t * 64;
        // ---- stage K tile (row-major bf16, XOR-swizzled 16B units) ----
#pragma unroll
        for (int r = 0; r < 4; ++r) {
            const int key = (tid >> 4) + 16 * r;
            f32x4 a = *(const f32x4*)(kb_ + (size_t)(kv0 + key) * (KVc * HDc) + kd0);
            short4v s4;
            s4[0] = f2bf(a[0]); s4[1] = f2bf(a[1]);
            s4[2] = f2bf(a[2]); s4[3] = f2bf(a[3]);
            *(short4v*)((char*)Ks + key * 128 + ((kunit ^ (key & 7)) << 4) + khalf) = s4;
        }
        // ---- stage V transposed ----
        {
            const float* r0 = vb_ + (size_t)(kv0 + vkey) * (KVc * HDc) + vd0;
            const float* r1 = r0 + KVc * HDc;
            f32x4 a0 = *(const f32x4*)(r0);
            f32x4 a1 = *(const f32x4*)(r0 + 4);
            f32x4 b0 = *(const f32x4*)(r1);
            f32x4 b1 = *(const f32x4*)(r1 + 4);
#pragma unroll
            for (int j = 0; j < 4; ++j) {
                unsigned pk0 = (unsigned short)f2bf(a0[j]) |
                               ((unsigned)(unsigned short)f2bf(b0[j]) << 16);
                unsigned pk1 = (unsigned short)f2bf(a1[j]) |
                               ((unsigned)(unsigned short)f2bf(b1[j]) << 16);
                *(unsigned*)&Vt[vd0 + j][vkey]     = pk0;
                *(unsigned*)&Vt[vd0 + 4 + j][vkey] = pk1;
            }
        }
        __syncthreads();

        // ---- S = Q K^T : 8 MFMAs (4 key-blocks x 2 dim-slices) ----
        f32x4 c[4];
#pragma unroll
        for (int kbk = 0; kbk < 4; ++kbk) {
            const int key = lr + 16 * kbk;
            const char* kr = (const char*)Ks + key * 128;
            bf16x8 k0 = *(const bf16x8*)(kr + ((lg       ^ (key & 7)) << 4));
            bf16x8 k1 = *(const bf16x8*)(kr + (((4 + lg) ^ (key & 7)) << 4));
            f32x4 acc = f32x4{0.f, 0.f, 0.f, 0.f};
            acc = __builtin_amdgcn_mfma_f32_16x16x32_bf16(qf[0], k0, acc, 0, 0, 0);
            acc = __builtin_amdgcn_mfma_f32_16x16x32_bf16(qf[1], k1, acc, 0, 0, 0);
            c[kbk] = acc;
        }

        // ---- causal mask (only the diagonal tile) ----
        if (t == ntiles - 1) {
#pragma unroll
            for (int kbk = 0; kbk < 4; ++kbk)
#pragma unroll
                for (int r = 0; r < 4; ++r)
                    if (kv0 + lr + 16 * kbk > qw0 + lg * 4 + r) c[kbk][r] = -1e30f;
        }

        // ---- online softmax (per query row r) ----
#pragma unroll
        for (int r = 0; r < 4; ++r) {
            float tm = fmaxf(fmaxf(c[0][r], c[1][r]), fmaxf(c[2][r], c[3][r]));
            tm = fmaxf(tm, __shfl_xor(tm, 1));
            tm = fmaxf(tm, __shfl_xor(tm, 2));
            tm = fmaxf(tm, __shfl_xor(tm, 4));
            tm = fmaxf(tm, __shfl_xor(tm, 8));
            const float mnew = fmaxf(mr[r], tm);
            const float corr = __expf(mr[r] - mnew);   // first tile: exp(-inf)=0
            mr[r] = mnew;
            float rs = 0.f;
#pragma unroll
            for (int kbk = 0; kbk < 4; ++kbk) {
                float p = __expf(c[kbk][r] - mnew);    // masked -> 0
                c[kbk][r] = p;
                rs += p;
            }
            rs += __shfl_xor(rs, 1);
            rs += __shfl_xor(rs, 2);
            rs += __shfl_xor(rs, 4);
            rs += __shfl_xor(rs, 8);
            ls[r] = ls[r] * corr + rs;
#pragma unroll
            for (int db = 0; db < 4; ++db) o[db][r] *= corr;
#pragma unroll
            for (int kbk = 0; kbk < 4; ++kbk)
                Ps[w][lg * 4 + r][lr + 16 * kbk] = f2bf(c[kbk][r]);
        }

        // ---- O += P V : 8 MFMAs (2 key-slices x 4 dim-blocks) ----
#pragma unroll
        for (int ks = 0; ks < 2; ++ks) {
            bf16x8 pa = *(const bf16x8*)&Ps[w][lr][lg * 8 + ks * 32];
#pragma unroll
            for (int db = 0; db < 4; ++db) {
                bf16x8 vv = *(const bf16x8*)&Vt[lr + 16 * db][lg * 8 + ks * 32];
                o[db] = __builtin_amdgcn_mfma_f32_16x16x32_bf16(pa, vv, o[db], 0, 0, 0);
            }
        }
        __syncthreads();     // protect Ks/Vt before next tile's staging
    }

    // ---- epilogue: normalize and store ----
#pragma unroll
    for (int r = 0; r < 4; ++r) {
        const float inv = 1.0f / ls[r];
        float* yp = y + ((size_t)(b * Tc + qw0 + lg * 4 + r) * Hc + h) * HDc;
#pragma unroll
        for (int db = 0; db < 4; ++db)
            yp[lr + 16 * db] = o[db][r] * inv;
    }
}

// ---------------------------------------------------------------------------
extern "C" void kernel_launch(void* const* d_in, const int* in_sizes, int n_in,
                              void* d_out, int out_size, void* d_ws, size_t ws_size,
                              hipStream_t stream) {
    const float* x    = (const float*)d_in[0];
    const float* Wq   = (const float*)d_in[1];
    const float* Wk   = (const float*)d_in[2];
    const float* Wv   = (const float*)d_in[3];
    const float* Wo   = (const float*)d_in[4];
    const float* cosT = (const float*)d_in[5];
    const float* sinT = (const float*)d_in[6];
    float* out = (float*)d_out;

    float* qbuf = (float*)d_ws;
    float* kbuf = qbuf + (size_t)Mrows * (Hc * HDc);
    float* vbuf = kbuf + (size_t)Mrows * (KVc * HDc);
    float* ybuf = vbuf + (size_t)Mrows * (KVc * HDc);

    dim3 blk(16, 16);
    gemm64<<<dim3((Hc * HDc) / 64, Mrows / 64), blk, 0, stream>>>(x, Wq, qbuf, Mrows, Hc * HDc, Dc);
    gemm64<<<dim3((KVc * HDc) / 64, Mrows / 64), blk, 0, stream>>>(x, Wk, kbuf, Mrows, KVc * HDc, Dc);
    gemm64<<<dim3((KVc * HDc) / 64, Mrows / 64), blk, 0, stream>>>(x, Wv, vbuf, Mrows, KVc * HDc, Dc);

    {
        int totalQ = Mrows * Hc * 32;
        rope_kernel<<<(totalQ + 255) / 256, 256, 0, stream>>>(qbuf, cosT, sinT, Hc, totalQ);
        int totalK = Mrows * KVc * 32;
        rope_kernel<<<(totalK + 255) / 256, 256, 0, stream>>>(kbuf, cosT, sinT, KVc, totalK);
    }

    // MFMA flash attention: 32 q-tiles x 32 heads x 2 batch
    attn_mfma<<<dim3(Tc / 64, Hc, Bc), 256, 0, stream>>>(qbuf, kbuf, vbuf, ybuf);

    gemm64<<<dim3(Dc / 64, Mrows / 64), blk, 0, stream>>>(ybuf, Wo, out, Mrows, Dc, Dc);
}

// Round 4
// 527.489 us; speedup vs baseline: 10.0777x; 3.1612x over previous
//
#include <hip/hip_runtime.h>
#include <hip/hip_bf16.h>

// Problem constants (from reference)
constexpr int Bc  = 2;
constexpr int Tc  = 2048;
constexpr int Dc  = 2048;
constexpr int Hc  = 32;
constexpr int KVc = 8;
constexpr int HDc = 64;
constexpr int Mrows = Bc * Tc;          // 4096
constexpr int QKVW  = 3072;             // fused q|k|v width
constexpr float SCALE = 0.125f;         // 1/sqrt(64)

typedef __attribute__((ext_vector_type(8))) short  bf16x8;
typedef __attribute__((ext_vector_type(4))) short  short4v;
typedef __attribute__((ext_vector_type(4))) float  f32x4;

__device__ __forceinline__ short f2bf(float f) {     // fp32 -> bf16 (RNE)
    unsigned u = __builtin_bit_cast(unsigned, f);
    unsigned r = (u + 0x7FFFu + ((u >> 16) & 1u)) >> 16;
    return (short)(unsigned short)r;
}

__device__ __forceinline__ void load_lds16(const void* g, void* l) {
    __builtin_amdgcn_global_load_lds(
        (const __attribute__((address_space(1))) unsigned int*)g,
        (__attribute__((address_space(3))) unsigned int*)l,
        16, 0, 0);
}

// ---------------------------------------------------------------------------
// fp32 -> bf16 elementwise convert (n multiple of 8)
// ---------------------------------------------------------------------------
__global__ void conv_bf16(const float* __restrict__ in, short* __restrict__ out, int n) {
    int i = (blockIdx.x * blockDim.x + threadIdx.x) * 8;
    if (i >= n) return;
    f32x4 a = *(const f32x4*)(in + i);
    f32x4 b = *(const f32x4*)(in + i + 4);
    bf16x8 o;
    o[0] = f2bf(a[0]); o[1] = f2bf(a[1]); o[2] = f2bf(a[2]); o[3] = f2bf(a[3]);
    o[4] = f2bf(b[0]); o[5] = f2bf(b[1]); o[6] = f2bf(b[2]); o[7] = f2bf(b[3]);
    *(bf16x8*)(out + i) = o;
}

// ---------------------------------------------------------------------------
// Transpose + convert: in fp32 [K x N] row-major -> out bf16 rows = N-columns.
// out[(n0r + n) * ldo + k] = bf16(in[k][n]).  64x64 tiles through LDS.
// ---------------------------------------------------------------------------
__global__ __launch_bounds__(256) void transpose_conv(const float* __restrict__ in,
                                                      short* __restrict__ out,
                                                      int N, int ldo, int n0r) {
    __shared__ float T[64][68];
    const int k0 = blockIdx.y * 64;
    const int n0 = blockIdx.x * 64;
    const int t  = threadIdx.x;
    const int c4 = (t & 15) * 4;
    const int rr = t >> 4;
#pragma unroll
    for (int r = 0; r < 4; ++r) {
        int k = rr + 16 * r;
        float4 v = *(const float4*)(in + (size_t)(k0 + k) * N + n0 + c4);
        *(float4*)&T[k][c4] = v;
    }
    __syncthreads();
#pragma unroll
    for (int r = 0; r < 4; ++r) {
        int n = rr + 16 * r;
        short4v s;
        s[0] = f2bf(T[c4 + 0][n]); s[1] = f2bf(T[c4 + 1][n]);
        s[2] = f2bf(T[c4 + 2][n]); s[3] = f2bf(T[c4 + 3][n]);
        *(short4v*)(out + (size_t)(n0r + n0 + n) * ldo + k0 + c4) = s;
    }
}

// ---------------------------------------------------------------------------
// bf16 MFMA GEMM (m97 structure): C[M,N] fp32 = A[M,K] @ Bt[N,K]^T.
// 128x128 tile, BK=64, 256 thr = 4 waves (2x2), wave tile 64x64 (4x4 frags).
// Staging via global_load_lds w=16 with pre-swizzled global source;
// ds_read_b128 fragments with matching XOR swizzle (16B unit ^ row&7).
// ---------------------------------------------------------------------------
__global__ __launch_bounds__(256) void gemm_mfma(const short* __restrict__ A,
                                                 const short* __restrict__ Bt,
                                                 float* __restrict__ C,
                                                 int M, int N, int K) {
    __shared__ short Al[128 * 64];   // 16 KB
    __shared__ short Bl[128 * 64];   // 16 KB
    const int tid = threadIdx.x;
    const int l  = tid & 63;
    const int w  = tid >> 6;
    const int lr = l & 15;
    const int lg = l >> 4;
    const int wm = w >> 1, wn = w & 1;
    const int bm = blockIdx.y * 128;
    const int bn = blockIdx.x * 128;

    f32x4 acc[4][4];
#pragma unroll
    for (int i = 0; i < 4; ++i)
#pragma unroll
        for (int j = 0; j < 4; ++j) acc[i][j] = f32x4{0.f, 0.f, 0.f, 0.f};

    // staging geometry: issue q (=w+4j) covers tile rows 8q..8q+7; lane i ->
    // row 8q + i/8, lds 16B-unit i%8; global unit = (i%8) ^ (row&7).
    const int srow_off = l >> 3;          // 0..7
    const int sunit    = l & 7;

    for (int k0 = 0; k0 < K; k0 += 64) {
        __syncthreads();                  // prior compute done reading LDS
#pragma unroll
        for (int j = 0; j < 4; ++j) {
            const int q   = w + 4 * j;
            const int row = 8 * q + srow_off;
            const int ug  = sunit ^ (row & 7);
            load_lds16(A  + (size_t)(bm + row) * K + k0 + ug * 8, (short*)Al + 512 * q);
            load_lds16(Bt + (size_t)(bn + row) * K + k0 + ug * 8, (short*)Bl + 512 * q);
        }
        __syncthreads();                  // staging drained (vmcnt0 @ barrier)

#pragma unroll
        for (int ks = 0; ks < 2; ++ks) {
            bf16x8 af[4], bf[4];
#pragma unroll
            for (int mb = 0; mb < 4; ++mb) {
                const int row = wm * 64 + mb * 16 + lr;
                const int u   = (ks * 4 + lg) ^ (row & 7);
                af[mb] = *(const bf16x8*)(Al + row * 64 + u * 8);
            }
#pragma unroll
            for (int nb = 0; nb < 4; ++nb) {
                const int row = wn * 64 + nb * 16 + lr;
                const int u   = (ks * 4 + lg) ^ (row & 7);
                bf[nb] = *(const bf16x8*)(Bl + row * 64 + u * 8);
            }
#pragma unroll
            for (int mb = 0; mb < 4; ++mb)
#pragma unroll
                for (int nb = 0; nb < 4; ++nb)
                    acc[mb][nb] = __builtin_amdgcn_mfma_f32_16x16x32_bf16(
                        af[mb], bf[nb], acc[mb][nb], 0, 0, 0);
        }
    }

#pragma unroll
    for (int mb = 0; mb < 4; ++mb)
#pragma unroll
        for (int r = 0; r < 4; ++r) {
            const int row = bm + wm * 64 + mb * 16 + lg * 4 + r;
            float* cp = C + (size_t)row * N + bn + wn * 64 + lr;
#pragma unroll
            for (int nb = 0; nb < 4; ++nb) cp[nb * 16] = acc[mb][nb][r];
        }
}

// ---------------------------------------------------------------------------
// RoPE in-place on fused qkv fp32 [Mrows][3072]: 32 q heads + 8 k heads.
// ---------------------------------------------------------------------------
__global__ void rope_fused(float* __restrict__ qkv,
                           const float* __restrict__ cosT,
                           const float* __restrict__ sinT, int total) {
    int idx = blockIdx.x * blockDim.x + threadIdx.x;
    if (idx >= total) return;
    int d   = idx & 31;
    int hh  = (idx >> 5) % 40;            // 0..31 q, 32..39 k
    int row = idx / (32 * 40);
    int t   = row & (Tc - 1);
    int col = (hh < 32) ? hh * 64 : 2048 + (hh - 32) * 64;
    float c = cosT[t * HDc + d];
    float s = sinT[t * HDc + d];
    float* p = qkv + (size_t)row * QKVW + col;
    float x0 = p[d];
    float x1 = p[d + 32];
    p[d]      = x0 * c - x1 * s;
    p[d + 32] = x1 * c + x0 * s;
}

// ---------------------------------------------------------------------------
// bf16 MFMA flash attention (round-3 structure; reads fused fp32 qkv,
// writes bf16 y for the Wo MFMA GEMM).
// ---------------------------------------------------------------------------
__global__ __launch_bounds__(256) void attn_mfma(const float* __restrict__ qkv,
                                                 short* __restrict__ yb) {
    __shared__ short Ks[64 * 64];
    __shared__ short Vt[64][72];
    __shared__ short Ps[4][16][72];

    const int tid = threadIdx.x;
    const int l   = tid & 63;
    const int w   = tid >> 6;
    const int lr  = l & 15;
    const int lg  = l >> 4;
    const int qt0 = blockIdx.x * 64;
    const int h   = blockIdx.y;
    const int b   = blockIdx.z;
    const int g   = h >> 2;
    const int qw0 = qt0 + w * 16;

    bf16x8 qf[2];
    {
        const float* qrow = qkv + (size_t)(b * Tc + qw0 + lr) * QKVW + h * 64;
#pragma unroll
        for (int s = 0; s < 2; ++s) {
            f32x4 a0 = *(const f32x4*)(qrow + s * 32 + lg * 8);
            f32x4 a1 = *(const f32x4*)(qrow + s * 32 + lg * 8 + 4);
            bf16x8 t;
            t[0] = f2bf(a0[0] * SCALE); t[1] = f2bf(a0[1] * SCALE);
            t[2] = f2bf(a0[2] * SCALE); t[3] = f2bf(a0[3] * SCALE);
            t[4] = f2bf(a1[0] * SCALE); t[5] = f2bf(a1[1] * SCALE);
            t[6] = f2bf(a1[2] * SCALE); t[7] = f2bf(a1[3] * SCALE);
            qf[s] = t;
        }
    }

    f32x4 o[4];
#pragma unroll
    for (int i = 0; i < 4; ++i) o[i] = f32x4{0.f, 0.f, 0.f, 0.f};
    float mr[4], ls[4];
#pragma unroll
    for (int i = 0; i < 4; ++i) { mr[i] = -1e30f; ls[i] = 0.f; }

    const float* kb_ = qkv + (size_t)(b * Tc) * QKVW + 2048 + g * 64;
    const float* vb_ = qkv + (size_t)(b * Tc) * QKVW + 2560 + g * 64;
    const int ntiles = qt0 / 64 + 1;

    const int kd0   = (tid & 15) * 4;
    const int kunit = kd0 >> 3;
    const int khalf = (kd0 & 4) << 1;
    const int vkey  = (tid & 31) * 2;
    const int vd0   = (tid >> 5) * 8;

    for (int t = 0; t < ntiles; ++t) {
        const int kv0 = t * 64;
#pragma unroll
        for (int r = 0; r < 4; ++r) {
            const int key = (tid >> 4) + 16 * r;
            f32x4 a = *(const f32x4*)(kb_ + (size_t)(kv0 + key) * QKVW + kd0);
            short4v s4;
            s4[0] = f2bf(a[0]); s4[1] = f2bf(a[1]);
            s4[2] = f2bf(a[2]); s4[3] = f2bf(a[3]);
            *(short4v*)((char*)Ks + key * 128 + ((kunit ^ (key & 7)) << 4) + khalf) = s4;
        }
        {
            const float* r0 = vb_ + (size_t)(kv0 + vkey) * QKVW + vd0;
            const float* r1 = r0 + QKVW;
            f32x4 a0 = *(const f32x4*)(r0);
            f32x4 a1 = *(const f32x4*)(r0 + 4);
            f32x4 b0 = *(const f32x4*)(r1);
            f32x4 b1 = *(const f32x4*)(r1 + 4);
#pragma unroll
            for (int j = 0; j < 4; ++j) {
                unsigned pk0 = (unsigned short)f2bf(a0[j]) |
                               ((unsigned)(unsigned short)f2bf(b0[j]) << 16);
                unsigned pk1 = (unsigned short)f2bf(a1[j]) |
                               ((unsigned)(unsigned short)f2bf(b1[j]) << 16);
                *(unsigned*)&Vt[vd0 + j][vkey]     = pk0;
                *(unsigned*)&Vt[vd0 + 4 + j][vkey] = pk1;
            }
        }
        __syncthreads();

        f32x4 c[4];
#pragma unroll
        for (int kbk = 0; kbk < 4; ++kbk) {
            const int key = lr + 16 * kbk;
            const char* kr = (const char*)Ks + key * 128;
            bf16x8 k0 = *(const bf16x8*)(kr + ((lg       ^ (key & 7)) << 4));
            bf16x8 k1 = *(const bf16x8*)(kr + (((4 + lg) ^ (key & 7)) << 4));
            f32x4 acc = f32x4{0.f, 0.f, 0.f, 0.f};
            acc = __builtin_amdgcn_mfma_f32_16x16x32_bf16(qf[0], k0, acc, 0, 0, 0);
            acc = __builtin_amdgcn_mfma_f32_16x16x32_bf16(qf[1], k1, acc, 0, 0, 0);
            c[kbk] = acc;
        }

        if (t == ntiles - 1) {
#pragma unroll
            for (int kbk = 0; kbk < 4; ++kbk)
#pragma unroll
                for (int r = 0; r < 4; ++r)
                    if (kv0 + lr + 16 * kbk > qw0 + lg * 4 + r) c[kbk][r] = -1e30f;
        }

#pragma unroll
        for (int r = 0; r < 4; ++r) {
            float tm = fmaxf(fmaxf(c[0][r], c[1][r]), fmaxf(c[2][r], c[3][r]));
            tm = fmaxf(tm, __shfl_xor(tm, 1));
            tm = fmaxf(tm, __shfl_xor(tm, 2));
            tm = fmaxf(tm, __shfl_xor(tm, 4));
            tm = fmaxf(tm, __shfl_xor(tm, 8));
            const float mnew = fmaxf(mr[r], tm);
            const float corr = __expf(mr[r] - mnew);
            mr[r] = mnew;
            float rs = 0.f;
#pragma unroll
            for (int kbk = 0; kbk < 4; ++kbk) {
                float p = __expf(c[kbk][r] - mnew);
                c[kbk][r] = p;
                rs += p;
            }
            rs += __shfl_xor(rs, 1);
            rs += __shfl_xor(rs, 2);
            rs += __shfl_xor(rs, 4);
            rs += __shfl_xor(rs, 8);
            ls[r] = ls[r] * corr + rs;
#pragma unroll
            for (int db = 0; db < 4; ++db) o[db][r] *= corr;
#pragma unroll
            for (int kbk = 0; kbk < 4; ++kbk)
                Ps[w][lg * 4 + r][lr + 16 * kbk] = f2bf(c[kbk][r]);
        }

#pragma unroll
        for (int ks = 0; ks < 2; ++ks) {
            bf16x8 pa = *(const bf16x8*)&Ps[w][lr][lg * 8 + ks * 32];
#pragma unroll
            for (int db = 0; db < 4; ++db) {
                bf16x8 vv = *(const bf16x8*)&Vt[lr + 16 * db][lg * 8 + ks * 32];
                o[db] = __builtin_amdgcn_mfma_f32_16x16x32_bf16(pa, vv, o[db], 0, 0, 0);
            }
        }
        __syncthreads();
    }

#pragma unroll
    for (int r = 0; r < 4; ++r) {
        const float inv = 1.0f / ls[r];
        short* yp = yb + (size_t)(b * Tc + qw0 + lg * 4 + r) * Dc + h * 64;
#pragma unroll
        for (int db = 0; db < 4; ++db)
            yp[lr + 16 * db] = f2bf(o[db][r] * inv);
    }
}

// ---------------------------------------------------------------------------
extern "C" void kernel_launch(void* const* d_in, const int* in_sizes, int n_in,
                              void* d_out, int out_size, void* d_ws, size_t ws_size,
                              hipStream_t stream) {
    const float* x    = (const float*)d_in[0];
    const float* Wq   = (const float*)d_in[1];
    const float* Wk   = (const float*)d_in[2];
    const float* Wv   = (const float*)d_in[3];
    const float* Wo   = (const float*)d_in[4];
    const float* cosT = (const float*)d_in[5];
    const float* sinT = (const float*)d_in[6];
    float* out = (float*)d_out;

    // workspace layout
    short* xb    = (short*)d_ws;                            // 4096x2048 bf16 (16MB)
    short* Wqkvt = xb + (size_t)Mrows * Dc;                 // 3072x2048 bf16 (12MB)
    short* Wot   = Wqkvt + (size_t)QKVW * Dc;               // 2048x2048 bf16 (8MB)
    short* ybuf  = Wot + (size_t)Dc * Dc;                   // 4096x2048 bf16 (16MB)
    float* qkv   = (float*)(ybuf + (size_t)Mrows * Dc);     // 4096x3072 f32 (48MB)

    // 1) converts / packed weight transposes
    conv_bf16<<<(Mrows * Dc / 8 + 255) / 256, 256, 0, stream>>>(x, xb, Mrows * Dc);
    transpose_conv<<<dim3(Dc / 64, Dc / 64), 256, 0, stream>>>(Wq, Wqkvt, Dc, Dc, 0);
    transpose_conv<<<dim3(512 / 64, Dc / 64), 256, 0, stream>>>(Wk, Wqkvt, 512, Dc, 2048);
    transpose_conv<<<dim3(512 / 64, Dc / 64), 256, 0, stream>>>(Wv, Wqkvt, 512, Dc, 2560);
    transpose_conv<<<dim3(Dc / 64, Dc / 64), 256, 0, stream>>>(Wo, Wot, Dc, Dc, 0);

    // 2) fused QKV projection: [4096,3072] = xb @ Wqkvt^T
    gemm_mfma<<<dim3(QKVW / 128, Mrows / 128), 256, 0, stream>>>(xb, Wqkvt, qkv, Mrows, QKVW, Dc);

    // 3) RoPE on q + k heads
    {
        int total = Mrows * (Hc + KVc) * 32;
        rope_fused<<<(total + 255) / 256, 256, 0, stream>>>(qkv, cosT, sinT, total);
    }

    // 4) flash attention -> bf16 y
    attn_mfma<<<dim3(Tc / 64, Hc, Bc), 256, 0, stream>>>(qkv, ybuf);

    // 5) output projection: out = y @ Wo
    gemm_mfma<<<dim3(Dc / 128, Mrows / 128), 256, 0, stream>>>(ybuf, Wot, out, Mrows, Dc, Dc);
}

// Round 5
// 525.321 us; speedup vs baseline: 10.1192x; 1.0041x over previous
//
#include <hip/hip_runtime.h>
#include <hip/hip_bf16.h>

// Problem constants (from reference)
constexpr int Bc  = 2;
constexpr int Tc  = 2048;
constexpr int Dc  = 2048;
constexpr int Hc  = 32;
constexpr int KVc = 8;
constexpr int HDc = 64;
constexpr int Mrows = Bc * Tc;          // 4096
constexpr int QKVW  = 3072;             // fused q|k|v width
constexpr float SCALE = 0.125f;         // 1/sqrt(64)

typedef __attribute__((ext_vector_type(8))) short  bf16x8;
typedef __attribute__((ext_vector_type(4))) short  short4v;
typedef __attribute__((ext_vector_type(4))) float  f32x4;

__device__ __forceinline__ short f2bf(float f) {     // fp32 -> bf16 (RNE)
    unsigned u = __builtin_bit_cast(unsigned, f);
    unsigned r = (u + 0x7FFFu + ((u >> 16) & 1u)) >> 16;
    return (short)(unsigned short)r;
}

__device__ __forceinline__ void load_lds16(const void* g, void* l) {
    __builtin_amdgcn_global_load_lds(
        (const __attribute__((address_space(1))) unsigned int*)g,
        (__attribute__((address_space(3))) unsigned int*)l,
        16, 0, 0);
}

// ---------------------------------------------------------------------------
// fp32 -> bf16 elementwise convert (n multiple of 8)
// ---------------------------------------------------------------------------
__global__ void conv_bf16(const float* __restrict__ in, short* __restrict__ out, int n) {
    int i = (blockIdx.x * blockDim.x + threadIdx.x) * 8;
    if (i >= n) return;
    f32x4 a = *(const f32x4*)(in + i);
    f32x4 b = *(const f32x4*)(in + i + 4);
    bf16x8 o;
    o[0] = f2bf(a[0]); o[1] = f2bf(a[1]); o[2] = f2bf(a[2]); o[3] = f2bf(a[3]);
    o[4] = f2bf(b[0]); o[5] = f2bf(b[1]); o[6] = f2bf(b[2]); o[7] = f2bf(b[3]);
    *(bf16x8*)(out + i) = o;
}

// ---------------------------------------------------------------------------
// Transpose + convert: in fp32 [K x N] row-major -> out bf16 rows = N-columns.
// ---------------------------------------------------------------------------
__global__ __launch_bounds__(256) void transpose_conv(const float* __restrict__ in,
                                                      short* __restrict__ out,
                                                      int N, int ldo, int n0r) {
    __shared__ float T[64][68];
    const int k0 = blockIdx.y * 64;
    const int n0 = blockIdx.x * 64;
    const int t  = threadIdx.x;
    const int c4 = (t & 15) * 4;
    const int rr = t >> 4;
#pragma unroll
    for (int r = 0; r < 4; ++r) {
        int k = rr + 16 * r;
        float4 v = *(const float4*)(in + (size_t)(k0 + k) * N + n0 + c4);
        *(float4*)&T[k][c4] = v;
    }
    __syncthreads();
#pragma unroll
    for (int r = 0; r < 4; ++r) {
        int n = rr + 16 * r;
        short4v s;
        s[0] = f2bf(T[c4 + 0][n]); s[1] = f2bf(T[c4 + 1][n]);
        s[2] = f2bf(T[c4 + 2][n]); s[3] = f2bf(T[c4 + 3][n]);
        *(short4v*)(out + (size_t)(n0r + n0 + n) * ldo + k0 + c4) = s;
    }
}

// ---------------------------------------------------------------------------
// bf16 MFMA GEMM (m97 structure) with XCD-aware block swizzle.
// C[M,N] fp32 = A[M,K] @ Bt[N,K]^T.  Grid blocks must be divisible by 8.
// ---------------------------------------------------------------------------
__global__ __launch_bounds__(256) void gemm_mfma(const short* __restrict__ A,
                                                 const short* __restrict__ Bt,
                                                 float* __restrict__ C,
                                                 int M, int N, int K) {
    __shared__ short Al[128 * 64];
    __shared__ short Bl[128 * 64];
    const int tid = threadIdx.x;
    const int l  = tid & 63;
    const int w  = tid >> 6;
    const int lr = l & 15;
    const int lg = l >> 4;
    const int wm = w >> 1, wn = w & 1;

    // XCD swizzle (nwg % 8 == 0 for all our grids)
    const int nwg = gridDim.x * gridDim.y;
    const int bid0 = blockIdx.y * gridDim.x + blockIdx.x;
    const int cpx = nwg >> 3;
    const int swz = (bid0 & 7) * cpx + (bid0 >> 3);
    const int bm = (swz / gridDim.x) * 128;
    const int bn = (swz % gridDim.x) * 128;

    f32x4 acc[4][4];
#pragma unroll
    for (int i = 0; i < 4; ++i)
#pragma unroll
        for (int j = 0; j < 4; ++j) acc[i][j] = f32x4{0.f, 0.f, 0.f, 0.f};

    const int srow_off = l >> 3;
    const int sunit    = l & 7;

    for (int k0 = 0; k0 < K; k0 += 64) {
        __syncthreads();
#pragma unroll
        for (int j = 0; j < 4; ++j) {
            const int q   = w + 4 * j;
            const int row = 8 * q + srow_off;
            const int ug  = sunit ^ (row & 7);
            load_lds16(A  + (size_t)(bm + row) * K + k0 + ug * 8, (short*)Al + 512 * q);
            load_lds16(Bt + (size_t)(bn + row) * K + k0 + ug * 8, (short*)Bl + 512 * q);
        }
        __syncthreads();

#pragma unroll
        for (int ks = 0; ks < 2; ++ks) {
            bf16x8 af[4], bf[4];
#pragma unroll
            for (int mb = 0; mb < 4; ++mb) {
                const int row = wm * 64 + mb * 16 + lr;
                const int u   = (ks * 4 + lg) ^ (row & 7);
                af[mb] = *(const bf16x8*)(Al + row * 64 + u * 8);
            }
#pragma unroll
            for (int nb = 0; nb < 4; ++nb) {
                const int row = wn * 64 + nb * 16 + lr;
                const int u   = (ks * 4 + lg) ^ (row & 7);
                bf[nb] = *(const bf16x8*)(Bl + row * 64 + u * 8);
            }
#pragma unroll
            for (int mb = 0; mb < 4; ++mb)
#pragma unroll
                for (int nb = 0; nb < 4; ++nb)
                    acc[mb][nb] = __builtin_amdgcn_mfma_f32_16x16x32_bf16(
                        af[mb], bf[nb], acc[mb][nb], 0, 0, 0);
        }
    }

#pragma unroll
    for (int mb = 0; mb < 4; ++mb)
#pragma unroll
        for (int r = 0; r < 4; ++r) {
            const int row = bm + wm * 64 + mb * 16 + lg * 4 + r;
            float* cp = C + (size_t)row * N + bn + wn * 64 + lr;
#pragma unroll
            for (int nb = 0; nb < 4; ++nb) cp[nb * 16] = acc[mb][nb][r];
        }
}

// ---------------------------------------------------------------------------
// RoPE + pack: qkv fp32 [Mrows][3072] -> qb bf16 [b][h][t][64] (scaled),
// kb bf16 [b][g][t][64].  One thread per (row, head, d<32).
// ---------------------------------------------------------------------------
__global__ void rope_pack_qk(const float* __restrict__ qkv,
                             const float* __restrict__ cosT,
                             const float* __restrict__ sinT,
                             short* __restrict__ qb, short* __restrict__ kb,
                             int total) {
    int idx = blockIdx.x * blockDim.x + threadIdx.x;
    if (idx >= total) return;
    int d   = idx & 31;
    int hh  = (idx >> 5) % 40;            // 0..31 q heads, 32..39 k heads
    int row = idx / (32 * 40);            // b*T + t
    int t   = row & (Tc - 1);
    int b   = row >> 11;
    float c = cosT[t * HDc + d];
    float s = sinT[t * HDc + d];
    if (hh < 32) {
        const float* p = qkv + (size_t)row * QKVW + hh * 64;
        float x0 = p[d], x1 = p[d + 32];
        short* qp = qb + (((size_t)(b * Hc + hh) * Tc + t) * 64);
        qp[d]      = f2bf((x0 * c - x1 * s) * SCALE);
        qp[d + 32] = f2bf((x1 * c + x0 * s) * SCALE);
    } else {
        int g = hh - 32;
        const float* p = qkv + (size_t)row * QKVW + 2048 + g * 64;
        float x0 = p[d], x1 = p[d + 32];
        short* kp = kb + (((size_t)(b * KVc + g) * Tc + t) * 64);
        kp[d]      = f2bf(x0 * c - x1 * s);
        kp[d + 32] = f2bf(x1 * c + x0 * s);
    }
}

// ---------------------------------------------------------------------------
// V transpose + convert: qkv fp32 v-section -> vtb bf16 [b][g][d][T].
// Block handles one 64t x 64d tile of one (b,g).
// ---------------------------------------------------------------------------
__global__ __launch_bounds__(256) void pack_vt(const float* __restrict__ qkv,
                                               short* __restrict__ vtb) {
    __shared__ float T[64][68];
    const int t0 = blockIdx.x * 64;
    const int g  = blockIdx.y;
    const int b  = blockIdx.z;
    const int tt = threadIdx.x;
    const int c4 = (tt & 15) * 4;
    const int rr = tt >> 4;
    const float* src = qkv + 2560 + g * 64;
#pragma unroll
    for (int r = 0; r < 4; ++r) {
        int t = rr + 16 * r;
        float4 v = *(const float4*)(src + (size_t)(b * Tc + t0 + t) * QKVW + c4);
        *(float4*)&T[t][c4] = v;
    }
    __syncthreads();
    short* dst = vtb + ((size_t)(b * KVc + g) * 64) * Tc;
#pragma unroll
    for (int r = 0; r < 4; ++r) {
        int d = rr + 16 * r;
        short4v s;
        s[0] = f2bf(T[c4 + 0][d]); s[1] = f2bf(T[c4 + 1][d]);
        s[2] = f2bf(T[c4 + 2][d]); s[3] = f2bf(T[c4 + 3][d]);
        *(short4v*)(dst + (size_t)d * Tc + t0 + c4) = s;
    }
}

// ---------------------------------------------------------------------------
// Barrier-free bf16 MFMA flash attention.
// 1 wave per block; block bx handles q-tiles {bx, 127-bx} of (h,b) -> causal
// load balance (~34 64-key steps per block).  K and V^T MFMA fragments are
// loaded directly global->VGPR (bf16, L2/L3-resident); the only LDS is the
// per-wave 16x72 P relay (write <=2-pair aliasing, read bank-uniform).
// ---------------------------------------------------------------------------
__global__ __launch_bounds__(64) void attn_gqa(const short* __restrict__ qb,
                                               const short* __restrict__ kb,
                                               const short* __restrict__ vtb,
                                               short* __restrict__ yb) {
    __shared__ short Ps[16][72];
    const int l  = threadIdx.x;
    const int lr = l & 15;
    const int lg = l >> 4;
    const int h  = blockIdx.y;
    const int b  = blockIdx.z;
    const int g  = h >> 2;

    const short* qhb = qb  + ((size_t)(b * Hc  + h) * Tc) * 64;
    const short* khb = kb  + ((size_t)(b * KVc + g) * Tc) * 64;
    const short* vhb = vtb + ((size_t)(b * KVc + g) * 64) * Tc;

#pragma unroll
    for (int half = 0; half < 2; ++half) {
        const int j   = half ? (127 - (int)blockIdx.x) : (int)blockIdx.x;
        const int qt0 = j * 16;

        bf16x8 qf0 = *(const bf16x8*)(qhb + (size_t)(qt0 + lr) * 64 + lg * 8);
        bf16x8 qf1 = *(const bf16x8*)(qhb + (size_t)(qt0 + lr) * 64 + 32 + lg * 8);

        f32x4 o[4];
#pragma unroll
        for (int i = 0; i < 4; ++i) o[i] = f32x4{0.f, 0.f, 0.f, 0.f};
        float mr[4], ls[4];
#pragma unroll
        for (int i = 0; i < 4; ++i) { mr[i] = -1e30f; ls[i] = 0.f; }

        const int nsteps = (qt0 >> 6) + 1;
        for (int st = 0; st < nsteps; ++st) {
            const int kv0 = st * 64;

            // ---- S = Q K^T : B-frags straight from global kb ----
            f32x4 c[4];
#pragma unroll
            for (int kbk = 0; kbk < 4; ++kbk) {
                const short* kr = khb + (size_t)(kv0 + 16 * kbk + lr) * 64;
                bf16x8 k0 = *(const bf16x8*)(kr + lg * 8);
                bf16x8 k1 = *(const bf16x8*)(kr + 32 + lg * 8);
                f32x4 acc = f32x4{0.f, 0.f, 0.f, 0.f};
                acc = __builtin_amdgcn_mfma_f32_16x16x32_bf16(qf0, k0, acc, 0, 0, 0);
                acc = __builtin_amdgcn_mfma_f32_16x16x32_bf16(qf1, k1, acc, 0, 0, 0);
                c[kbk] = acc;
            }

            if (st == nsteps - 1) {          // causal mask on the diagonal step
#pragma unroll
                for (int kbk = 0; kbk < 4; ++kbk)
#pragma unroll
                    for (int r = 0; r < 4; ++r)
                        if (kv0 + lr + 16 * kbk > qt0 + lg * 4 + r) c[kbk][r] = -1e30f;
            }

            // ---- online softmax ----
#pragma unroll
            for (int r = 0; r < 4; ++r) {
                float tm = fmaxf(fmaxf(c[0][r], c[1][r]), fmaxf(c[2][r], c[3][r]));
                tm = fmaxf(tm, __shfl_xor(tm, 1));
                tm = fmaxf(tm, __shfl_xor(tm, 2));
                tm = fmaxf(tm, __shfl_xor(tm, 4));
                tm = fmaxf(tm, __shfl_xor(tm, 8));
                if (tm > mr[r]) {
                    const float corr = __expf(mr[r] - tm);
                    mr[r] = tm;
                    ls[r] *= corr;
#pragma unroll
                    for (int db = 0; db < 4; ++db) o[db][r] *= corr;
                }
                float rs = 0.f;
#pragma unroll
                for (int kbk = 0; kbk < 4; ++kbk) {
                    float p = __expf(c[kbk][r] - mr[r]);
                    c[kbk][r] = p;
                    rs += p;
                }
                rs += __shfl_xor(rs, 1);
                rs += __shfl_xor(rs, 2);
                rs += __shfl_xor(rs, 4);
                rs += __shfl_xor(rs, 8);
                ls[r] += rs;
#pragma unroll
                for (int kbk = 0; kbk < 4; ++kbk)
                    Ps[lg * 4 + r][lr + 16 * kbk] = f2bf(c[kbk][r]);
            }

            // ---- O += P V : A from P relay, B-frags straight from global vtb
#pragma unroll
            for (int ks = 0; ks < 2; ++ks) {
                bf16x8 pa = *(const bf16x8*)&Ps[lr][lg * 8 + ks * 32];
#pragma unroll
                for (int db = 0; db < 4; ++db) {
                    bf16x8 vv = *(const bf16x8*)(vhb + (size_t)(db * 16 + lr) * Tc
                                                 + kv0 + ks * 32 + lg * 8);
                    o[db] = __builtin_amdgcn_mfma_f32_16x16x32_bf16(pa, vv, o[db], 0, 0, 0);
                }
            }
        }

        // ---- epilogue ----
#pragma unroll
        for (int r = 0; r < 4; ++r) {
            const float inv = 1.0f / ls[r];
            short* yp = yb + (size_t)(b * Tc + qt0 + lg * 4 + r) * Dc + h * 64;
#pragma unroll
            for (int db = 0; db < 4; ++db)
                yp[lr + 16 * db] = f2bf(o[db][r] * inv);
        }
    }
}

// ---------------------------------------------------------------------------
extern "C" void kernel_launch(void* const* d_in, const int* in_sizes, int n_in,
                              void* d_out, int out_size, void* d_ws, size_t ws_size,
                              hipStream_t stream) {
    const float* x    = (const float*)d_in[0];
    const float* Wq   = (const float*)d_in[1];
    const float* Wk   = (const float*)d_in[2];
    const float* Wv   = (const float*)d_in[3];
    const float* Wo   = (const float*)d_in[4];
    const float* cosT = (const float*)d_in[5];
    const float* sinT = (const float*)d_in[6];
    float* out = (float*)d_out;

    // workspace layout (aliased stages, ~100 MB total)
    short* xb    = (short*)d_ws;                            // [4096,2048] bf16
    short* Wqkvt = xb + (size_t)Mrows * Dc;                 // [3072,2048] bf16
    short* Wot   = Wqkvt + (size_t)QKVW * Dc;               // [2048,2048] bf16
    short* ybuf  = Wot + (size_t)Dc * Dc;                   // [4096,2048] bf16
    float* qkv   = (float*)(ybuf + (size_t)Mrows * Dc);     // [4096,3072] f32
    // after the QKV GEMM, xb/Wqkvt are dead -> reuse for packed q/k/vt
    short* qbp = xb;                                        // [2,32,2048,64] bf16 (16MB)
    short* kbp = Wqkvt;                                     // [2,8,2048,64]  bf16 (4MB)
    short* vtb = Wqkvt + (size_t)Bc * KVc * Tc * 64;        // [2,8,64,2048]  bf16 (4MB)

    // 1) converts / packed weight transposes
    conv_bf16<<<(Mrows * Dc / 8 + 255) / 256, 256, 0, stream>>>(x, xb, Mrows * Dc);
    transpose_conv<<<dim3(Dc / 64, Dc / 64), 256, 0, stream>>>(Wq, Wqkvt, Dc, Dc, 0);
    transpose_conv<<<dim3(512 / 64, Dc / 64), 256, 0, stream>>>(Wk, Wqkvt, 512, Dc, 2048);
    transpose_conv<<<dim3(512 / 64, Dc / 64), 256, 0, stream>>>(Wv, Wqkvt, 512, Dc, 2560);
    transpose_conv<<<dim3(Dc / 64, Dc / 64), 256, 0, stream>>>(Wo, Wot, Dc, Dc, 0);

    // 2) fused QKV projection: [4096,3072] = xb @ Wqkvt^T
    gemm_mfma<<<dim3(QKVW / 128, Mrows / 128), 256, 0, stream>>>(xb, Wqkvt, qkv, Mrows, QKVW, Dc);

    // 3) RoPE + pack to bf16 attention layouts (overwrites xb/Wqkvt regions)
    {
        int total = Mrows * (Hc + KVc) * 32;
        rope_pack_qk<<<(total + 255) / 256, 256, 0, stream>>>(qkv, cosT, sinT, qbp, kbp, total);
        pack_vt<<<dim3(Tc / 64, KVc, Bc), 256, 0, stream>>>(qkv, vtb);
    }

    // 4) barrier-free flash attention -> bf16 y
    attn_gqa<<<dim3(64, Hc, Bc), 64, 0, stream>>>(qbp, kbp, vtb, ybuf);

    // 5) output projection: out = y @ Wo
    gemm_mfma<<<dim3(Dc / 128, Mrows / 128), 256, 0, stream>>>(ybuf, Wot, out, Mrows, Dc, Dc);
}